// Round 2
// baseline (24906.976 us; speedup 1.0000x reference)
//
#include <hip/hip_runtime.h>
#include <hip/hip_bf16.h>

#define DIMS 1024
#define SEQ 512
#define BATCH 128
#define VOCAB 32000
#define GRID 256

typedef __attribute__((ext_vector_type(8))) short short8;
typedef __attribute__((ext_vector_type(4))) float f32x4;

__device__ __forceinline__ ushort f2bf(float x) {
    union { float f; unsigned u; } v; v.f = x;
    unsigned u = v.u;
    return (ushort)((u + 0x7FFFu + ((u >> 16) & 1u)) >> 16);
}

__global__ void conv_emb_kernel(const float* __restrict__ in, ushort* __restrict__ out, int n) {
    int idx = blockIdx.x * blockDim.x + threadIdx.x;
    int stride = gridDim.x * blockDim.x;
    for (int i = idx * 4; i < n; i += stride * 4) {
        float4 v = *(const float4*)(in + i);
        ushort4 o;
        o.x = f2bf(v.x); o.y = f2bf(v.y); o.z = f2bf(v.z); o.w = f2bf(v.w);
        *(ushort4*)(out + i) = o;
    }
}

// Persistent LSTM kernel, flag-synchronized.
// Grid = 256 blocks = 2 row-groups (64 batch rows) x 128 d-chunks (8 d cols).
// Per step: x@W half first (no dependency), poll producer flags of own
// row-group, h@U half, activations, coalesced h write, release flag.
// h layout: [parity][rg][chunk=cb][64 rows][8 cols] bf16 -> block writes one
// contiguous 1KB chunk; readers do 16B vector loads.
__launch_bounds__(256, 1)
__global__ void lstm_kernel(const int* __restrict__ feats,
                            const ushort* __restrict__ emb,
                            const float* __restrict__ Wf, const float* __restrict__ Uf, const float* __restrict__ bfp,
                            const float* __restrict__ Wi, const float* __restrict__ Ui, const float* __restrict__ bip,
                            const float* __restrict__ Wo, const float* __restrict__ Uo, const float* __restrict__ bop,
                            const float* __restrict__ Wc, const float* __restrict__ Uc, const float* __restrict__ bcp,
                            ushort* __restrict__ hbuf, float* __restrict__ out, int* __restrict__ flags) {
    __shared__ ushort Bl[32 * 2048];                 // 131072 B: B-slice, XOR-swizzled
    __shared__ float pre[64][33];                    // preactivation staging
    __shared__ __align__(16) ushort hsh[512];        // h staging for coalesced write

    const int tid = threadIdx.x;
    const int bid = blockIdx.x;
    const int rg = bid >> 7;      // row group: rows rg*64 .. rg*64+63
    const int cb = bid & 127;     // d-chunk: d = cb*8 .. cb*8+7

    // ---- one-time: load B slice (f32 -> bf16) into LDS ----
    // iterate cl fastest so global reads are 32B-coalesced per gate
    for (int idx = tid; idx < 32 * 2048; idx += 256) {
        int cl = idx & 31;
        int k  = idx >> 5;
        int g  = cl >> 3, dd = cl & 7;
        int d  = cb * 8 + dd;
        const float* Wg = (g == 0) ? Wf : (g == 1) ? Wi : (g == 2) ? Wo : Wc;
        const float* Ug = (g == 0) ? Uf : (g == 1) ? Ui : (g == 2) ? Uo : Uc;
        float v = (k < 1024) ? Wg[k * 1024 + d] : Ug[(k - 1024) * 1024 + d];
        int boff = ((cl << 12) | (k << 1)) ^ ((cl & 7) << 4);
        *(ushort*)((char*)Bl + boff) = f2bf(v);
    }
    __syncthreads();

    const int lane = tid & 63;
    const int w  = tid >> 6;           // wave 0..3, owns rows w*16..w*16+15
    const int lx = lane & 15;          // A-frag row / B-frag col within tile
    const int qq = lane >> 4;          // quarter
    const int kg = qq * 8;             // k sub-offset within a 32-k step
    const int brow = rg * 64 + w * 16 + lx;   // global batch row for A-frag
    const int lr = w * 16 + lx;               // local row within row-group

    const int bofs0 = (lx << 12) ^ ((lx & 7) << 4);
    const int bofs1 = ((16 + lx) << 12) ^ ((lx & 7) << 4);

    // per-thread biases (states sid = tid*2+{0,1}: row = sid>>3, dd = sid&7)
    float bF[2], bI[2], bO[2], bC[2];
    #pragma unroll
    for (int s = 0; s < 2; s++) {
        int dd = (tid * 2 + s) & 7;
        int d = cb * 8 + dd;
        bF[s] = bfp[d]; bI[s] = bip[d]; bO[s] = bop[d]; bC[s] = bcp[d];
    }

    float cst[2] = {0.f, 0.f};
    int* myflags = flags + rg * 128;
    int fidx = feats[brow * SEQ];

    for (int t = 0; t < SEQ; t++) {
        const ushort* xrow = emb + (size_t)fidx * DIMS;
        int fnxt = (t + 1 < SEQ) ? feats[brow * SEQ + t + 1] : 0;

        f32x4 acc0 = {0.f, 0.f, 0.f, 0.f};
        f32x4 acc1 = {0.f, 0.f, 0.f, 0.f};

        // x @ W part: k = 0..1023 (independent of h -> before the poll)
        #pragma unroll 8
        for (int ks = 0; ks < 32; ks++) {
            int k = ks * 32 + kg;
            short8 a  = *(const short8*)(xrow + k);
            short8 b0 = *(const short8*)((const char*)Bl + (bofs0 ^ (k << 1)));
            short8 b1 = *(const short8*)((const char*)Bl + (bofs1 ^ (k << 1)));
            acc0 = __builtin_amdgcn_mfma_f32_16x16x32_bf16(a, b0, acc0, 0, 0, 0);
            acc1 = __builtin_amdgcn_mfma_f32_16x16x32_bf16(a, b1, acc1, 0, 0, 0);
        }
        fidx = fnxt;

        if (t > 0) {
            // wait for all 128 producers of this row-group to publish h_t
            long guard = 0;
            for (;;) {
                int f0 = __hip_atomic_load(myflags + lane,      __ATOMIC_RELAXED, __HIP_MEMORY_SCOPE_AGENT);
                int f1 = __hip_atomic_load(myflags + 64 + lane, __ATOMIC_RELAXED, __HIP_MEMORY_SCOPE_AGENT);
                if (__all(f0 >= t && f1 >= t)) break;
                __builtin_amdgcn_s_sleep(2);
                if (++guard > 200000000L) break;  // deadlock safety valve
            }
            __threadfence();  // acquire: make producers' h stores visible

            const ushort* hbase = hbuf + (size_t)((t & 1) * 2 + rg) * 128 * 512;
            // h @ U part: k = 1024..2047
            #pragma unroll 8
            for (int ks = 0; ks < 32; ks++) {
                const ushort* hp = hbase + (ks * 4 + qq) * 512 + lr * 8;
                short8 a  = *(const short8*)hp;
                int k = 1024 + ks * 32 + kg;
                short8 b0 = *(const short8*)((const char*)Bl + (bofs0 ^ (k << 1)));
                short8 b1 = *(const short8*)((const char*)Bl + (bofs1 ^ (k << 1)));
                acc0 = __builtin_amdgcn_mfma_f32_16x16x32_bf16(a, b0, acc0, 0, 0, 0);
                acc1 = __builtin_amdgcn_mfma_f32_16x16x32_bf16(a, b1, acc1, 0, 0, 0);
            }
        }

        // C/D layout (m89): col = lane&15, row = (lane>>4)*4 + reg
        int r0 = w * 16 + qq * 4;
        #pragma unroll
        for (int j = 0; j < 4; j++) {
            pre[r0 + j][lx]      = acc0[j];
            pre[r0 + j][16 + lx] = acc1[j];
        }
        __syncthreads();

        // elementwise gates + state update: 512 (row,dd) states, 2 per thread
        #pragma unroll
        for (int s = 0; s < 2; s++) {
            int sid = tid * 2 + s;
            int row = sid >> 3;
            int dd  = sid & 7;
            float pf = pre[row][dd]      + bF[s];
            float pi = pre[row][8 + dd]  + bI[s];
            float po = pre[row][16 + dd] + bO[s];
            float pc = pre[row][24 + dd] + bC[s];
            float f  = 1.f / (1.f + __expf(-pf));
            float ig = 1.f / (1.f + __expf(-pi));
            float o  = 1.f / (1.f + __expf(-po));
            float e2 = __expf(2.f * pc);
            float cc = (e2 - 1.f) / (e2 + 1.f);
            float cn = f * cst[s] + ig * cc;
            cst[s] = cn;
            float e2c = __expf(2.f * cn);
            float th  = (e2c - 1.f) / (e2c + 1.f);
            float h   = o * th;
            hsh[sid] = f2bf(h);
            if (t == SEQ - 1) {
                int grow = rg * 64 + row;
                int d = cb * 8 + dd;
                out[grow * 2048 + d] = h;
                out[grow * 2048 + 1024 + d] = cn;
            }
        }
        __syncthreads();   // hsh ready; also separates pre reads from next-step pre writes

        if (t < SEQ - 1) {
            // coalesced 1KB chunk write by wave 0
            if (tid < 64) {
                ushort* hw = hbuf + (size_t)(((t + 1) & 1) * 2 + rg) * 128 * 512
                                  + (size_t)cb * 512 + tid * 8;
                *(int4*)hw = ((const int4*)hsh)[tid];
            }
            __threadfence();   // release: h stores visible before flag
            if (tid == 0) {
                __hip_atomic_store(myflags + cb, t + 1, __ATOMIC_RELEASE, __HIP_MEMORY_SCOPE_AGENT);
            }
        }
    }
}

extern "C" void kernel_launch(void* const* d_in, const int* in_sizes, int n_in,
                              void* d_out, int out_size, void* d_ws, size_t ws_size,
                              hipStream_t stream) {
    const int*   feats = (const int*)d_in[0];
    const float* emb_f = (const float*)d_in[1];
    const float* Wf = (const float*)d_in[2];
    const float* Uf = (const float*)d_in[3];
    const float* bf_ = (const float*)d_in[4];
    const float* Wi = (const float*)d_in[5];
    const float* Ui = (const float*)d_in[6];
    const float* bi_ = (const float*)d_in[7];
    const float* Wo = (const float*)d_in[8];
    const float* Uo = (const float*)d_in[9];
    const float* bo_ = (const float*)d_in[10];
    const float* Wc = (const float*)d_in[11];
    const float* Uc = (const float*)d_in[12];
    const float* bc_ = (const float*)d_in[13];

    char* ws = (char*)d_ws;
    ushort* emb_bf = (ushort*)ws;                          // 65,536,000 B
    ushort* hbuf   = (ushort*)(ws + 65536000);             // 2x2x128x64x8 bf16 = 524,288 B
    int*    flags  = (int*)(ws + 65536000 + 524288);       // 256 flags

    hipMemsetAsync(flags, 0, 1024, stream);
    conv_emb_kernel<<<1024, 256, 0, stream>>>(emb_f, emb_bf, VOCAB * DIMS);
    lstm_kernel<<<GRID, 256, 0, stream>>>(feats, emb_bf,
                                          Wf, Uf, bf_, Wi, Ui, bi_,
                                          Wo, Uo, bo_, Wc, Uc, bc_,
                                          hbuf, (float*)d_out, flags);
}

// Round 3
// 4480.679 us; speedup vs baseline: 5.5588x; 5.5588x over previous
//
#include <hip/hip_runtime.h>
#include <hip/hip_bf16.h>

#define DIMS 1024
#define SEQ 512
#define BATCH 128
#define VOCAB 32000
#define GRID 256

typedef __attribute__((ext_vector_type(8))) short short8;
typedef __attribute__((ext_vector_type(4))) float f32x4;

__device__ __forceinline__ ushort f2bf(float x) {
    union { float f; unsigned u; } v; v.f = x;
    unsigned u = v.u;
    return (ushort)((u + 0x7FFFu + ((u >> 16) & 1u)) >> 16);
}

__global__ void conv_emb_kernel(const float* __restrict__ in, ushort* __restrict__ out, int n) {
    int idx = blockIdx.x * blockDim.x + threadIdx.x;
    int stride = gridDim.x * blockDim.x;
    for (int i = idx * 4; i < n; i += stride * 4) {
        float4 v = *(const float4*)(in + i);
        ushort4 o;
        o.x = f2bf(v.x); o.y = f2bf(v.y); o.z = f2bf(v.z); o.w = f2bf(v.w);
        *(ushort4*)(out + i) = o;
    }
}

// Persistent LSTM kernel, fence-free flag sync.
// Grid = 256 blocks = 2 row-groups (64 batch rows) x 128 d-chunks (8 d cols).
// All cross-block traffic (h + flags) uses agent-scope relaxed atomics
// (sc0/sc1 per-instruction coherence) -> NO threadfence / L2 wb/inv per step.
// Gates computed in-register via shfl_xor(8) pair exchange (lanes lx and
// lx^8 hold f,o and i,c columns for the same rows) -> no pre[] LDS staging,
// one barrier per step (before the flag store).
__launch_bounds__(256, 1)
__global__ void lstm_kernel(const int* __restrict__ feats,
                            const ushort* __restrict__ emb,
                            const float* __restrict__ Wf, const float* __restrict__ Uf, const float* __restrict__ bfp,
                            const float* __restrict__ Wi, const float* __restrict__ Ui, const float* __restrict__ bip,
                            const float* __restrict__ Wo, const float* __restrict__ Uo, const float* __restrict__ bop,
                            const float* __restrict__ Wc, const float* __restrict__ Uc, const float* __restrict__ bcp,
                            ushort* __restrict__ hbuf, float* __restrict__ out, int* __restrict__ flags) {
    __shared__ ushort Bl[32 * 2048];   // 131072 B: B-slice, XOR-swizzled

    const int tid = threadIdx.x;
    const int bid = blockIdx.x;
    const int rg = bid >> 7;      // row group: rows rg*64 .. rg*64+63
    const int cb = bid & 127;     // d-chunk: d = cb*8 .. cb*8+7

    // ---- one-time: load B slice (f32 -> bf16) into LDS ----
    for (int idx = tid; idx < 32 * 2048; idx += 256) {
        int cl = idx & 31;
        int k  = idx >> 5;
        int g  = cl >> 3, dd0 = cl & 7;
        int dw  = cb * 8 + dd0;
        const float* Wg = (g == 0) ? Wf : (g == 1) ? Wi : (g == 2) ? Wo : Wc;
        const float* Ug = (g == 0) ? Uf : (g == 1) ? Ui : (g == 2) ? Uo : Uc;
        float v = (k < 1024) ? Wg[k * 1024 + dw] : Ug[(k - 1024) * 1024 + dw];
        int boff = ((cl << 12) | (k << 1)) ^ ((cl & 7) << 4);
        *(ushort*)((char*)Bl + boff) = f2bf(v);
    }
    __syncthreads();

    const int lane = tid & 63;
    const int w  = tid >> 6;           // wave 0..3, owns rows w*16..w*16+15
    const int lx = lane & 15;          // A-frag row / B-frag col within tile
    const int qq = lane >> 4;          // quarter
    const int kg = qq * 8;             // k sub-offset within a 32-k step
    const int brow = rg * 64 + w * 16 + lx;   // global batch row for A-frag
    const int lr = w * 16 + lx;               // local row within row-group

    const int bofs0 = (lx << 12) ^ ((lx & 7) << 4);
    const int bofs1 = ((16 + lx) << 12) ^ ((lx & 7) << 4);

    // gate-pair exchange roles: lanes lx<8 hold f (acc0) / o (acc1) for dd=lx,
    // lanes lx>=8 hold i (acc0) / c (acc1) for dd=lx-8. Partner = lane ^ 8.
    const int sel = (lx >> 3) & 1;     // 0: f/o owner (handles rows j=0,1), 1: i/c owner (rows j=2,3)
    const int dd  = lx & 7;
    const int d   = cb * 8 + dd;
    const float bF = bfp[d], bI = bip[d], bO = bop[d], bC = bcp[d];

    float cst[2] = {0.f, 0.f};
    int* myflags = flags + rg * 128;
    int fidx = feats[brow * SEQ];

    for (int t = 0; t < SEQ; t++) {
        const ushort* xrow = emb + (size_t)fidx * DIMS;
        int fnxt = (t + 1 < SEQ) ? feats[brow * SEQ + t + 1] : 0;

        f32x4 acc0 = {0.f, 0.f, 0.f, 0.f};
        f32x4 acc1 = {0.f, 0.f, 0.f, 0.f};

        // x @ W part: k = 0..1023 (independent of h -> before the poll)
        #pragma unroll 8
        for (int ks = 0; ks < 32; ks++) {
            int k = ks * 32 + kg;
            short8 a  = *(const short8*)(xrow + k);
            short8 b0 = *(const short8*)((const char*)Bl + (bofs0 ^ (k << 1)));
            short8 b1 = *(const short8*)((const char*)Bl + (bofs1 ^ (k << 1)));
            acc0 = __builtin_amdgcn_mfma_f32_16x16x32_bf16(a, b0, acc0, 0, 0, 0);
            acc1 = __builtin_amdgcn_mfma_f32_16x16x32_bf16(a, b1, acc1, 0, 0, 0);
        }
        fidx = fnxt;

        if (t > 0) {
            // wait for all 128 producers of this row-group to publish h_t
            long guard = 0;
            for (;;) {
                int f0 = __hip_atomic_load(myflags + lane,      __ATOMIC_RELAXED, __HIP_MEMORY_SCOPE_AGENT);
                int f1 = __hip_atomic_load(myflags + 64 + lane, __ATOMIC_RELAXED, __HIP_MEMORY_SCOPE_AGENT);
                if (__all(f0 >= t && f1 >= t)) break;
                __builtin_amdgcn_s_sleep(1);
                if (++guard > 100000000L) break;  // deadlock safety valve
            }

            // h @ U part: k = 1024..2047; sc1 loads (bypass stale L1/L2)
            const ushort* hbase = hbuf + (size_t)((t & 1) * 2 + rg) * (128 * 512);
            #pragma unroll 8
            for (int ks = 0; ks < 32; ks++) {
                const unsigned long long* hp =
                    (const unsigned long long*)(hbase + ((ks * 4 + qq) << 9) + lr * 8);
                union { unsigned long long u[2]; short8 v; } av;
                av.u[0] = __hip_atomic_load(hp,     __ATOMIC_RELAXED, __HIP_MEMORY_SCOPE_AGENT);
                av.u[1] = __hip_atomic_load(hp + 1, __ATOMIC_RELAXED, __HIP_MEMORY_SCOPE_AGENT);
                int k = 1024 + ks * 32 + kg;
                short8 b0 = *(const short8*)((const char*)Bl + (bofs0 ^ (k << 1)));
                short8 b1 = *(const short8*)((const char*)Bl + (bofs1 ^ (k << 1)));
                acc0 = __builtin_amdgcn_mfma_f32_16x16x32_bf16(av.v, b0, acc0, 0, 0, 0);
                acc1 = __builtin_amdgcn_mfma_f32_16x16x32_bf16(av.v, b1, acc1, 0, 0, 0);
            }
        }

        // ---- in-register gate exchange (partner = lane^8) ----
        // I handle rows jA..jA+1 (jA = sel*2); partner handles the other two.
        // Send partner its rows' values, receive mine.
        float ra0[2], ra1[2];
        #pragma unroll
        for (int k2 = 0; k2 < 2; k2++) {
            ra0[k2] = __shfl_xor(sel ? acc0[k2] : acc0[2 + k2], 8);
            ra1[k2] = __shfl_xor(sel ? acc1[k2] : acc1[2 + k2], 8);
        }
        ushort* hnext = hbuf + (size_t)(((t + 1) & 1) * 2 + rg) * (128 * 512);
        #pragma unroll
        for (int k2 = 0; k2 < 2; k2++) {
            float own0 = sel ? acc0[2 + k2] : acc0[k2];   // acc0[jA+k2]
            float own1 = sel ? acc1[2 + k2] : acc1[k2];   // acc1[jA+k2]
            float pf = (sel ? ra0[k2] : own0) + bF;
            float pi = (sel ? own0 : ra0[k2]) + bI;
            float po = (sel ? ra1[k2] : own1) + bO;
            float pc = (sel ? own1 : ra1[k2]) + bC;
            float f  = 1.f / (1.f + __expf(-pf));
            float ig = 1.f / (1.f + __expf(-pi));
            float o  = 1.f / (1.f + __expf(-po));
            float e2 = __expf(2.f * pc);
            float cc = (e2 - 1.f) / (e2 + 1.f);
            float cn = f * cst[k2] + ig * cc;
            cst[k2] = cn;
            float e2c = __expf(2.f * cn);
            float th  = (e2c - 1.f) / (e2c + 1.f);
            float h   = o * th;
            int lr2 = w * 16 + qq * 4 + sel * 2 + k2;     // local row of this state
            if (t < SEQ - 1) {
                // write-through (sc1) store: visible at coherence point, no fence
                __hip_atomic_store(hnext + cb * 512 + lr2 * 8 + dd, f2bf(h),
                                   __ATOMIC_RELAXED, __HIP_MEMORY_SCOPE_AGENT);
            } else {
                int grow = rg * 64 + lr2;
                out[grow * 2048 + d] = h;
                out[grow * 2048 + 1024 + d] = cn;
            }
        }

        if (t < SEQ - 1) {
            asm volatile("s_waitcnt vmcnt(0)" ::: "memory");  // h stores acked at coherence point
            __syncthreads();                                   // all 4 waves done
            if (tid == 0) {
                __hip_atomic_store(myflags + cb, t + 1, __ATOMIC_RELAXED, __HIP_MEMORY_SCOPE_AGENT);
            }
        }
    }
}

extern "C" void kernel_launch(void* const* d_in, const int* in_sizes, int n_in,
                              void* d_out, int out_size, void* d_ws, size_t ws_size,
                              hipStream_t stream) {
    const int*   feats = (const int*)d_in[0];
    const float* emb_f = (const float*)d_in[1];
    const float* Wf = (const float*)d_in[2];
    const float* Uf = (const float*)d_in[3];
    const float* bf_ = (const float*)d_in[4];
    const float* Wi = (const float*)d_in[5];
    const float* Ui = (const float*)d_in[6];
    const float* bi_ = (const float*)d_in[7];
    const float* Wo = (const float*)d_in[8];
    const float* Uo = (const float*)d_in[9];
    const float* bo_ = (const float*)d_in[10];
    const float* Wc = (const float*)d_in[11];
    const float* Uc = (const float*)d_in[12];
    const float* bc_ = (const float*)d_in[13];

    char* ws = (char*)d_ws;
    ushort* emb_bf = (ushort*)ws;                          // 65,536,000 B
    ushort* hbuf   = (ushort*)(ws + 65536000);             // 2x2x128x64x8 bf16 = 524,288 B
    int*    flags  = (int*)(ws + 65536000 + 524288);       // 256 flags

    hipMemsetAsync(flags, 0, 1024, stream);
    conv_emb_kernel<<<1024, 256, 0, stream>>>(emb_f, emb_bf, VOCAB * DIMS);
    lstm_kernel<<<GRID, 256, 0, stream>>>(feats, emb_bf,
                                          Wf, Uf, bf_, Wi, Ui, bi_,
                                          Wo, Uo, bo_, Wc, Uc, bc_,
                                          hbuf, (float*)d_out, flags);
}